// Round 16
// baseline (133.136 us; speedup 1.0000x reference)
//
#include <hip/hip_runtime.h>
#include <hip/hip_bf16.h>

#define L_ 2048
#define B_ 2
#define E_ 1024
#define H_ 16
#define HD_ 64
#define TOPK_ 64
#define MROWS (B_*L_)
#define SCALE 0.125f

typedef __attribute__((ext_vector_type(8))) short short8;
typedef __attribute__((ext_vector_type(4))) short short4v;
typedef __attribute__((ext_vector_type(4))) float f32x4;

static __device__ __forceinline__ short f2bf(float f) {
    __hip_bfloat16 h = __float2bfloat16(f);
    return *reinterpret_cast<short*>(&h);
}

// ---- merged: xsum partials FIRST (512 blks, 4-acc unrolled) + transpose + casts ----
__global__ void k_prep(const float* __restrict__ q,
                       const float* __restrict__ w0, const float* __restrict__ w1,
                       const float* __restrict__ w2, const float* __restrict__ w3,
                       short* __restrict__ xb,
                       short* __restrict__ o0, short* __restrict__ o1,
                       short* __restrict__ o2, short* __restrict__ o3,
                       float* __restrict__ xpart) {
    int blk = blockIdx.x;
    if (blk < 512) {
        int cg = blk & 7, ch = blk >> 3;   // ch 0..63
        int col = cg * 256 + threadIdx.x;
        const float* qp = q + (size_t)(ch * 32) * (B_ * E_) + col;
        float s0 = 0.f, s1 = 0.f, s2 = 0.f, s3 = 0.f;
#pragma unroll
        for (int l = 0; l < 32; l += 4) {
            s0 += qp[(size_t)(l + 0) * (B_ * E_)];
            s1 += qp[(size_t)(l + 1) * (B_ * E_)];
            s2 += qp[(size_t)(l + 2) * (B_ * E_)];
            s3 += qp[(size_t)(l + 3) * (B_ * E_)];
        }
        xpart[ch * (B_ * E_) + col] = (s0 + s1) + (s2 + s3);
    } else if (blk < 4608) {
        int i = (blk - 512) * 256 + threadIdx.x;
        int idx = i * 4;
        int e = idx & (E_ - 1);
        int l = (idx >> 10) & (L_ - 1);
        int b = idx >> 21;
        float4 v = *reinterpret_cast<const float4*>(q + l * (B_ * E_) + b * E_ + e);
        short4v o;
        o[0] = f2bf(v.x); o[1] = f2bf(v.y); o[2] = f2bf(v.z); o[3] = f2bf(v.w);
        *reinterpret_cast<short4v*>(xb + idx) = o;
    } else {
        int cb = blk - 4608;
        int sel = cb >> 10, lb = cb & 1023;
        const float* w = sel == 0 ? w0 : sel == 1 ? w1 : sel == 2 ? w2 : w3;
        short* o = sel == 0 ? o0 : sel == 1 ? o1 : sel == 2 ? o2 : o3;
        int i = lb * 256 + threadIdx.x;
        float4 v = *reinterpret_cast<const float4*>(w + i * 4);
        short4v s;
        s[0] = f2bf(v.x); s[1] = f2bf(v.y); s[2] = f2bf(v.z); s[3] = f2bf(v.w);
        *reinterpret_cast<short4v*>(o + i * 4) = s;
    }
}

// ---- GEMM core: dbuf 2-phase + T2 swizzle, 512 threads / 8 waves.
// Compile-time MODE + dynamic LDS (rounds 11-13 lessons).
template<int MODE, int BM, int BN>
__device__ __forceinline__ void gemm_body(const short* __restrict__ A,
                                          const short* __restrict__ Bw,
                                          const float* __restrict__ bias,
                                          short* __restrict__ Cb,
                                          float* __restrict__ Cf,
                                          const float* __restrict__ ident,
                                          int bx, int by) {
    const int K = E_;
    constexpr int MI = BM / 32;
    constexpr int NI = BN / 64;
    extern __shared__ short smem[];
    short* As = smem;
    short* Bs = smem + 2 * BM * 64;
    int tid = threadIdx.x;
    int lane = tid & 63;
    int wid = tid >> 6;
    int wr = wid >> 2, wc = wid & 3;
    int lrow = lane & 15;
    int kg = lane >> 4;
    int lr8 = lane >> 3;
    int swz = (((lane & 7) ^ (lr8 & 7)) * 8);
    int rx = lrow & 7;
    int mBase = by * BM, nBase = bx * BN;

    auto STAGE = [&](int buf, int k0) {
#pragma unroll
        for (int i = 0; i < BM / 64; ++i) {
            int r0 = (wid * (BM / 64) + i) * 8;
            const short* ga = A + (size_t)(mBase + r0 + lr8) * K + k0 + swz;
            __builtin_amdgcn_global_load_lds(
                (const __attribute__((address_space(1))) void*)ga,
                (__attribute__((address_space(3))) void*)(As + buf * BM * 64 + r0 * 64), 16, 0, 0);
        }
#pragma unroll
        for (int i = 0; i < BN / 64; ++i) {
            int r0 = (wid * (BN / 64) + i) * 8;
            const short* gb = Bw + (size_t)(nBase + r0 + lr8) * K + k0 + swz;
            __builtin_amdgcn_global_load_lds(
                (const __attribute__((address_space(1))) void*)gb,
                (__attribute__((address_space(3))) void*)(Bs + buf * BN * 64 + r0 * 64), 16, 0, 0);
        }
    };

    f32x4 acc[MI][NI];
#pragma unroll
    for (int i = 0; i < MI; ++i)
#pragma unroll
        for (int j = 0; j < NI; ++j) acc[i][j] = (f32x4){0.f, 0.f, 0.f, 0.f};

    STAGE(0, 0);
    asm volatile("s_waitcnt vmcnt(0)" ::: "memory");
    __syncthreads();

    int cur = 0;
    for (int k0 = 0; k0 < K; k0 += 64) {
        if (k0 + 64 < K) STAGE(cur ^ 1, k0 + 64);

        short8 af[2][MI], bf[2][NI];
#pragma unroll
        for (int kk = 0; kk < 2; ++kk) {
#pragma unroll
            for (int mi = 0; mi < MI; ++mi)
                af[kk][mi] = *reinterpret_cast<const short8*>(
                    As + cur * BM * 64 + (wr * (MI * 16) + mi * 16 + lrow) * 64 + (((kk * 4 + kg) ^ rx) * 8));
#pragma unroll
            for (int ni = 0; ni < NI; ++ni)
                bf[kk][ni] = *reinterpret_cast<const short8*>(
                    Bs + cur * BN * 64 + (wc * (NI * 16) + ni * 16 + lrow) * 64 + (((kk * 4 + kg) ^ rx) * 8));
        }
#pragma unroll
        for (int kk = 0; kk < 2; ++kk)
#pragma unroll
            for (int mi = 0; mi < MI; ++mi)
#pragma unroll
                for (int ni = 0; ni < NI; ++ni)
                    acc[mi][ni] = __builtin_amdgcn_mfma_f32_16x16x32_bf16(
                        af[kk][mi], bf[kk][ni], acc[mi][ni], 0, 0, 0);

        asm volatile("s_waitcnt vmcnt(0)" ::: "memory");
        __syncthreads();
        cur ^= 1;
    }

    int rowq = (lane >> 4) * 4;
    int coll = lane & 15;
#pragma unroll
    for (int mi = 0; mi < MI; ++mi) {
#pragma unroll
        for (int ni = 0; ni < NI; ++ni) {
            int col = nBase + wc * (NI * 16) + ni * 16 + coll;
            float bv = bias[col];
            int row0 = mBase + wr * (MI * 16) + mi * 16 + rowq;
            if (MODE == 2) {
                int b = row0 >> 11, l = row0 & (L_ - 1);
                short4v sv;
#pragma unroll
                for (int r = 0; r < 4; ++r) sv[r] = f2bf(acc[mi][ni][r] + bv);
                *reinterpret_cast<short4v*>(
                    Cb + ((size_t)((b * H_ + (col >> 6)) * 64 + (col & 63))) * 2048 + l) = sv;
            } else if (MODE == 1) {
#pragma unroll
                for (int r = 0; r < 4; ++r) {
                    int row = row0 + r;
                    int b = row >> 11, l = row & (L_ - 1);
                    size_t oi = (size_t)l * (B_ * E_) + b * E_ + col;
                    Cf[oi] = acc[mi][ni][r] + bv + ident[oi];
                }
            } else {
#pragma unroll
                for (int r = 0; r < 4; ++r)
                    Cb[(size_t)(row0 + r) * E_ + col] = f2bf(acc[mi][ni][r] + bv);
            }
        }
    }
}

// ---- score body (512 threads): partial scores over e-quarters; same per-(h,n)
// f32 summation order -> bit-identical scorp -> identical top-k ----
__device__ __forceinline__ void score_body(const float* __restrict__ query,
                                           const float* __restrict__ tb,
                                           float* __restrict__ scorp, int id) {
    extern __shared__ short smem[];
    float* xs = (float*)smem;             // [64][68]
    float* ts = (float*)smem + 64 * 68;   // [16][68]
    int eq = id >> 6;
    int b = (id >> 5) & 1;
    int n0 = (id & 31) * 64;
    int tid = threadIdx.x;                // 0..511
    int hg = tid & 7, rg = tid >> 3;      // rg 0..63
    float acc0 = 0.f, acc1 = 0.f;
    for (int e0 = eq * 256; e0 < eq * 256 + 256; e0 += 64) {
        __syncthreads();
        for (int j = tid; j < 1024; j += 512) {
            int r = j >> 4, c4 = (j & 15) * 4;
            float4 v = *reinterpret_cast<const float4*>(
                &query[(size_t)(n0 + r) * (B_ * E_) + b * E_ + e0 + c4]);
            *reinterpret_cast<float4*>(&xs[r * 68 + c4]) = v;
        }
        if (tid < 256) {
            int hh = tid >> 4, c4 = (tid & 15) * 4;
            float4 v = *reinterpret_cast<const float4*>(&tb[(size_t)(b * 16 + hh) * E_ + e0 + c4]);
            *reinterpret_cast<float4*>(&ts[hh * 68 + c4]) = v;
        }
        __syncthreads();
        for (int c = 0; c < 64; ++c) {
            float x0 = xs[rg * 68 + c];
            acc0 += x0 * ts[hg * 68 + c];
            acc1 += x0 * ts[(hg + 8) * 68 + c];
        }
    }
    scorp[(size_t)eq * 65536 + (size_t)(b * 16 + hg) * L_ + n0 + rg] = acc0;
    scorp[(size_t)eq * 65536 + (size_t)(b * 16 + hg + 8) * L_ + n0 + rg] = acc1;
}

// ---- merged dispatch: blocks 0..767 = q/k/v projections; 768..1023 = scores ----
__global__ __launch_bounds__(512) void k_gemm3(const short* __restrict__ A,
    const short* __restrict__ W0, const short* __restrict__ W1, const short* __restrict__ W2,
    const float* __restrict__ b0, const float* __restrict__ b1, const float* __restrict__ b2,
    short* __restrict__ C0, short* __restrict__ C1, short* __restrict__ vtb,
    const float* __restrict__ query, const float* __restrict__ tb,
    float* __restrict__ scorp) {
    int wg = blockIdx.x;
    if (wg < 768) {
        int sw = (wg & 7) * 96 + (wg >> 3);
        int bx = sw & 7, by = (sw >> 3) & 31, z = sw >> 8;
        if (z == 2)
            gemm_body<2, 128, 128>(A, W2, b2, vtb, nullptr, nullptr, bx, by);
        else if (z == 1)
            gemm_body<0, 128, 128>(A, W1, b1, C1, nullptr, nullptr, bx, by);
        else
            gemm_body<0, 128, 128>(A, W0, b0, C0, nullptr, nullptr, bx, by);
    } else {
        score_body(query, tb, scorp, wg - 768);
    }
}

__global__ __launch_bounds__(512) void k_gemmo(const short* __restrict__ A,
                                               const short* __restrict__ Bw,
                                               const float* __restrict__ bias,
                                               float* __restrict__ C,
                                               const float* __restrict__ ident) {
    int wg = blockIdx.x;
    int sw = (wg & 7) * 64 + (wg >> 3);
    int bx = sw & 15, by = sw >> 4;
    gemm_body<1, 128, 64>(A, Bw, bias, nullptr, C, ident, bx, by);
}

// ---- fused qsum + t: per (b,h) block computes t[b,h,:] from xpart (f32 exact) ----
__global__ __launch_bounds__(256) void k_qt(const float* __restrict__ xpart,
                                            const float* __restrict__ qw,
                                            const float* __restrict__ qb,
                                            const float* __restrict__ kw,
                                            float* __restrict__ tb) {
    __shared__ float xs[1024];
    __shared__ float pr[256];
    __shared__ float qs[64];
    int bh = blockIdx.x;              // grid 32
    int b = bh >> 4, h = bh & 15;
    int tid = threadIdx.x;
    for (int j = tid; j < 1024; j += 256) {
        float s = 0.f;
#pragma unroll
        for (int c = 0; c < 64; ++c) s += xpart[c * (B_ * E_) + b * E_ + j];
        xs[j] = s;
    }
    __syncthreads();
    int fl = tid >> 2, eq = tid & 3;
    int f = h * 64 + fl;
    float s = 0.f;
    for (int e = eq * 256; e < eq * 256 + 256; ++e) s += xs[e] * qw[(size_t)f * E_ + e];
    pr[tid] = s;
    __syncthreads();
    if (eq == 0)
        qs[fl] = ((pr[tid] + pr[tid + 1]) + pr[tid + 2]) + pr[tid + 3] + (float)L_ * qb[f];
    __syncthreads();
    float acc[4] = {0.f, 0.f, 0.f, 0.f};
    for (int d = 0; d < 64; ++d) {
        float qv = qs[d];
        float4 kv = *reinterpret_cast<const float4*>(kw + (size_t)(h * 64 + d) * E_ + tid * 4);
        acc[0] += qv * kv.x; acc[1] += qv * kv.y; acc[2] += qv * kv.z; acc[3] += qv * kv.w;
    }
    float4 o; o.x = acc[0]; o.y = acc[1]; o.z = acc[2]; o.w = acc[3];
    *reinterpret_cast<float4*>(tb + (size_t)bh * E_ + tid * 4) = o;
}

// ---- top-64 per (b,h): ballot-based radix-select + wide gather ----
__global__ __launch_bounds__(256) void k_sel(const float* __restrict__ scorp,
                                             const short* __restrict__ kb,
                                             short* __restrict__ selkb) {
    __shared__ int sel[4][64];
    int tid = threadIdx.x;
    int wid = tid >> 6, lane = tid & 63;
    int bh = blockIdx.x * 4 + wid;   // grid 8
    int b = bh >> 4, h = bh & 15;

    unsigned u[32];
#pragma unroll
    for (int j = 0; j < 32; ++j) {
        int base = bh * L_ + j * 64 + lane;
        float sc = ((scorp[base] + scorp[base + 65536]) + scorp[base + 131072]) + scorp[base + 196608];
        sc *= SCALE;
        unsigned bits = __float_as_uint(sc);
        u[j] = (bits & 0x80000000u) ? ~bits : (bits | 0x80000000u);
    }
    unsigned prefix = 0;
    int k = TOPK_;
    for (int bit = 31; bit >= 0; --bit) {
        unsigned cand = prefix | (1u << bit);
        unsigned cs = cand >> bit;
        int c = 0;
#pragma unroll
        for (int j = 0; j < 32; ++j)
            c += __popcll(__ballot((u[j] >> bit) == cs));
        if (c >= k) prefix = cand; else k -= c;
    }
    unsigned T = prefix;
    int nStrict = 0;
#pragma unroll
    for (int j = 0; j < 32; ++j) nStrict += __popcll(__ballot(u[j] > T));
    int nTies = TOPK_ - nStrict;

    int strictBase = 0, tieBase = 0;
    unsigned long long below = (lane == 0) ? 0ull : ((~0ull) >> (64 - lane));
#pragma unroll
    for (int j = 0; j < 32; ++j) {
        unsigned long long mS = __ballot(u[j] > T);
        unsigned long long mT = __ballot(u[j] == T);
        if (u[j] > T) {
            int slot = strictBase + __popcll(mS & below);
            sel[wid][slot] = j * 64 + lane;
        } else if (u[j] == T) {
            int r = tieBase + __popcll(mT & below);
            if (r < nTies) sel[wid][nStrict + r] = j * 64 + lane;
        }
        strictBase += __popcll(mS);
        tieBase += __popcll(mT);
    }
    __syncthreads();

    int idx8[8];
#pragma unroll
    for (int it = 0; it < 8; ++it) idx8[it] = sel[wid][it * 8 + (lane >> 3)];
#pragma unroll
    for (int it = 0; it < 8; ++it) {
        int m = it * 8 + (lane >> 3);
        const short* src = kb + ((size_t)b * L_ + idx8[it]) * E_ + h * HD_ + (lane & 7) * 8;
        short8 v = *reinterpret_cast<const short8*>(src);
        *reinterpret_cast<short8*>(
            selkb + (size_t)bh * 4096 + m * 64 + (((lane & 7) ^ (m & 7)) * 8)) = v;
    }
}

// ---- attW: S_k = k.selk^T (MFMA) -> softmax -> Wpart = P2^T v (MFMA) ----
__global__ __launch_bounds__(256) void k_attW(const short* __restrict__ kb,
                                              const short* __restrict__ vtb,
                                              const short* __restrict__ selkb,
                                              float* __restrict__ wpart) {
    __shared__ short sk[4096], kt[4096], vt[4096], pt[4096];
    int wg = blockIdx.x;
    int sw = (wg & 7) * 64 + (wg >> 3);
    int bh = sw & 31, ch = sw >> 5;
    int b = bh >> 4, h = bh & 15;
    int tid = threadIdx.x, w = tid >> 6, lane = tid & 63;
    int lr = lane & 15, kg = lane >> 4;

#pragma unroll
    for (int j = 0; j < 2; ++j) {
        int off = (w * 2 + j) * 512;
        __builtin_amdgcn_global_load_lds(
            (const __attribute__((address_space(1))) void*)(selkb + (size_t)bh * 4096 + off + lane * 8),
            (__attribute__((address_space(3))) void*)(sk + off), 16, 0, 0);
    }

    f32x4 accw[4];
#pragma unroll
    for (int i = 0; i < 4; ++i) accw[i] = (f32x4){0.f, 0.f, 0.f, 0.f};

    for (int t = 0; t < 2; ++t) {
        int lt = ch * 128 + t * 64;
#pragma unroll
        for (int j = 0; j < 2; ++j) {
            int r = w * 16 + j * 8 + (lane >> 3);
            int s = lane & 7;
            const short* src = kb + ((size_t)(b * L_ + lt + r)) * E_ + h * 64 + ((s ^ (r & 7)) * 8);
            __builtin_amdgcn_global_load_lds(
                (const __attribute__((address_space(1))) void*)src,
                (__attribute__((address_space(3))) void*)(kt + (w * 16 + j * 8) * 64), 16, 0, 0);
        }
        __syncthreads();

        f32x4 s4[4];
#pragma unroll
        for (int i = 0; i < 4; ++i) s4[i] = (f32x4){0.f, 0.f, 0.f, 0.f};
#pragma unroll
        for (int kk = 0; kk < 2; ++kk) {
            int row = w * 16 + lr;
            short8 a = *reinterpret_cast<const short8*>(
                kt + row * 64 + (((kk * 4 + kg) ^ (row & 7)) * 8));
#pragma unroll
            for (int ni = 0; ni < 4; ++ni) {
                int m = ni * 16 + lr;
                short8 bb = *reinterpret_cast<const short8*>(
                    sk + m * 64 + (((kk * 4 + kg) ^ (m & 7)) * 8));
                s4[ni] = __builtin_amdgcn_mfma_f32_16x16x32_bf16(a, bb, s4[ni], 0, 0, 0);
            }
        }
        float p[4][4];
#pragma unroll
        for (int r = 0; r < 4; ++r) {
            float v0 = s4[0][r] * SCALE, v1 = s4[1][r] * SCALE;
            float v2 = s4[2][r] * SCALE, v3 = s4[3][r] * SCALE;
            float mx = fmaxf(fmaxf(v0, v1), fmaxf(v2, v3));
            mx = fmaxf(mx, __shfl_xor(mx, 1));
            mx = fmaxf(mx, __shfl_xor(mx, 2));
            mx = fmaxf(mx, __shfl_xor(mx, 4));
            mx = fmaxf(mx, __shfl_xor(mx, 8));
            float e0 = __expf(v0 - mx), e1 = __expf(v1 - mx);
            float e2 = __expf(v2 - mx), e3 = __expf(v3 - mx);
            float sm = e0 + e1 + e2 + e3;
            sm += __shfl_xor(sm, 1);
            sm += __shfl_xor(sm, 2);
            sm += __shfl_xor(sm, 4);
            sm += __shfl_xor(sm, 8);
            float inv = 1.f / sm;
            p[0][r] = e0 * inv; p[1][r] = e1 * inv; p[2][r] = e2 * inv; p[3][r] = e3 * inv;
        }
#pragma unroll
        for (int ni = 0; ni < 4; ++ni)
#pragma unroll
            for (int r = 0; r < 4; ++r) {
                int m = ni * 16 + lr;
                int ll = w * 16 + kg * 4 + r;
                pt[m * 64 + (((ll >> 3) ^ (m & 7)) * 8) + (ll & 7)] = f2bf(p[ni][r]);
            }
#pragma unroll
        for (int j = 0; j < 2; ++j) {
            int d = w * 16 + j * 8 + (lane >> 3);
            int s = lane & 7;
            const short* src = vtb + ((size_t)(bh * 64 + d)) * 2048 + lt + ((s ^ (d & 7)) * 8);
            __builtin_amdgcn_global_load_lds(
                (const __attribute__((address_space(1))) void*)src,
                (__attribute__((address_space(3))) void*)(vt + (w * 16 + j * 8) * 64), 16, 0, 0);
        }
        __syncthreads();
#pragma unroll
        for (int kk = 0; kk < 2; ++kk) {
            int mm = w * 16 + lr;
            short8 a = *reinterpret_cast<const short8*>(
                pt + mm * 64 + (((kk * 4 + kg) ^ (mm & 7)) * 8));
#pragma unroll
            for (int ni = 0; ni < 4; ++ni) {
                int d = ni * 16 + lr;
                short8 bb = *reinterpret_cast<const short8*>(
                    vt + d * 64 + (((kk * 4 + kg) ^ (d & 7)) * 8));
                accw[ni] = __builtin_amdgcn_mfma_f32_16x16x32_bf16(a, bb, accw[ni], 0, 0, 0);
            }
        }
    }
#pragma unroll
    for (int ni = 0; ni < 4; ++ni)
#pragma unroll
        for (int r = 0; r < 4; ++r) {
            int m = w * 16 + kg * 4 + r;
            int d = ni * 16 + lr;
            wpart[((size_t)(ch * 32 + bh)) * 4096 + m * 64 + d] = accw[ni][r];
        }
}

// ---- attO: in-LDS W reduce (replaces k_wreduce) + S_q MFMA -> softmax -> P1.W ----
__global__ __launch_bounds__(256) void k_attO(const short* __restrict__ qb,
                                              const short* __restrict__ selkb,
                                              const float* __restrict__ wpart,
                                              short* __restrict__ att) {
    __shared__ short sk[4096], wt[4096], qt[4096], p1[4096];
    int wg = blockIdx.x;
    int sw = (wg & 7) * 64 + (wg >> 3);
    int bh = sw & 31, ch = sw >> 5;
    int b = bh >> 4, h = bh & 15;
    int tid = threadIdx.x, w = tid >> 6, lane = tid & 63;
    int lr = lane & 15, kg = lane >> 4;

#pragma unroll
    for (int j = 0; j < 2; ++j) {
        int off = (w * 2 + j) * 512;
        __builtin_amdgcn_global_load_lds(
            (const __attribute__((address_space(1))) void*)(selkb + (size_t)bh * 4096 + off + lane * 8),
            (__attribute__((address_space(3))) void*)(sk + off), 16, 0, 0);
    }

    // reduce this bh's 16 wpart chunks directly into wt LDS (same c-order + f2bf
    // as the old k_wreduce -> bit-identical W; layout identical to old wtg)
    for (int j = tid; j < 4096; j += 256) {
        float s = 0.f;
#pragma unroll
        for (int c = 0; c < 16; ++c) s += wpart[(size_t)c * 131072 + bh * 4096 + j];
        int m = j >> 6, d = j & 63;
        wt[d * 64 + (((m >> 3) ^ (d & 7)) * 8) + (m & 7)] = f2bf(s);
    }

    for (int t = 0; t < 2; ++t) {
        int lt = ch * 128 + t * 64;
#pragma unroll
        for (int j = 0; j < 2; ++j) {
            int r = w * 16 + j * 8 + (lane >> 3);
            int s = lane & 7;
            const short* src = qb + ((size_t)(b * L_ + lt + r)) * E_ + h * 64 + ((s ^ (r & 7)) * 8);
            __builtin_amdgcn_global_load_lds(
                (const __attribute__((address_space(1))) void*)src,
                (__attribute__((address_space(3))) void*)(qt + (w * 16 + j * 8) * 64), 16, 0, 0);
        }
        __syncthreads();

        f32x4 s4[4];
#pragma unroll
        for (int i = 0; i < 4; ++i) s4[i] = (f32x4){0.f, 0.f, 0.f, 0.f};
#pragma unroll
        for (int kk = 0; kk < 2; ++kk) {
            int row = w * 16 + lr;
            short8 a = *reinterpret_cast<const short8*>(
                qt + row * 64 + (((kk * 4 + kg) ^ (row & 7)) * 8));
#pragma unroll
            for (int ni = 0; ni < 4; ++ni) {
                int m = ni * 16 + lr;
                short8 bb = *reinterpret_cast<const short8*>(
                    sk + m * 64 + (((kk * 4 + kg) ^ (m & 7)) * 8));
                s4[ni] = __builtin_amdgcn_mfma_f32_16x16x32_bf16(a, bb, s4[ni], 0, 0, 0);
            }
        }
        float p[4][4];
#pragma unroll
        for (int r = 0; r < 4; ++r) {
            float v0 = s4[0][r] * SCALE, v1 = s4[1][r] * SCALE;
            float v2 = s4[2][r] * SCALE, v3 = s4[3][r] * SCALE;
            float mx = fmaxf(fmaxf(v0, v1), fmaxf(v2, v3));
            mx = fmaxf(mx, __shfl_xor(mx, 1));
            mx = fmaxf(mx, __shfl_xor(mx, 2));
            mx = fmaxf(mx, __shfl_xor(mx, 4));
            mx = fmaxf(mx, __shfl_xor(mx, 8));
            float e0 = __expf(v0 - mx), e1 = __expf(v1 - mx);
            float e2 = __expf(v2 - mx), e3 = __expf(v3 - mx);
            float sm = e0 + e1 + e2 + e3;
            sm += __shfl_xor(sm, 1);
            sm += __shfl_xor(sm, 2);
            sm += __shfl_xor(sm, 4);
            sm += __shfl_xor(sm, 8);
            float inv = 1.f / sm;
            p[0][r] = e0 * inv; p[1][r] = e1 * inv; p[2][r] = e2 * inv; p[3][r] = e3 * inv;
        }
#pragma unroll
        for (int ni = 0; ni < 4; ++ni)
#pragma unroll
            for (int r = 0; r < 4; ++r) {
                int m = ni * 16 + lr;
                int ll = w * 16 + kg * 4 + r;
                p1[ll * 64 + (((m >> 3) ^ (ll & 7)) * 8) + (m & 7)] = f2bf(p[ni][r]);
            }
        __syncthreads();
        f32x4 ao[4];
#pragma unroll
        for (int i = 0; i < 4; ++i) ao[i] = (f32x4){0.f, 0.f, 0.f, 0.f};
#pragma unroll
        for (int kk = 0; kk < 2; ++kk) {
            int row = w * 16 + lr;
            short8 a = *reinterpret_cast<const short8*>(
                p1 + row * 64 + (((kk * 4 + kg) ^ (row & 7)) * 8));
#pragma unroll
            for (int ni = 0; ni < 4; ++ni) {
                int d = ni * 16 + lr;
                short8 bb = *reinterpret_cast<const short8*>(
                    wt + d * 64 + (((kk * 4 + kg) ^ (d & 7)) * 8));
                ao[ni] = __builtin_amdgcn_mfma_f32_16x16x32_bf16(a, bb, ao[ni], 0, 0, 0);
            }
        }
#pragma unroll
        for (int ni = 0; ni < 4; ++ni)
#pragma unroll
            for (int r = 0; r < 4; ++r) {
                int l = lt + w * 16 + kg * 4 + r;
                int d = ni * 16 + lr;
                att[((size_t)(b * L_ + l)) * E_ + h * 64 + d] = f2bf(ao[ni][r]);
            }
    }
}

extern "C" void kernel_launch(void* const* d_in, const int* in_sizes, int n_in,
                              void* d_out, int out_size, void* d_ws, size_t ws_size,
                              hipStream_t stream) {
    const float* query = (const float*)d_in[0];
    const float* q_w = (const float*)d_in[1];
    const float* q_b = (const float*)d_in[2];
    const float* k_w = (const float*)d_in[3];
    const float* k_b = (const float*)d_in[4];
    const float* v_w = (const float*)d_in[5];
    const float* v_b = (const float*)d_in[6];
    const float* o_w = (const float*)d_in[7];
    const float* o_b = (const float*)d_in[8];
    float* out = (float*)d_out;

    char* p = (char*)d_ws;
    auto alloc = [&](size_t bytes) {
        char* r = p;
        p += (bytes + 255) & ~(size_t)255;
        return r;
    };
    short* xb    = (short*)alloc((size_t)MROWS * E_ * 2);
    short* qwb   = (short*)alloc((size_t)E_ * E_ * 2);
    short* kwb   = (short*)alloc((size_t)E_ * E_ * 2);
    short* vwb   = (short*)alloc((size_t)E_ * E_ * 2);
    short* owb   = (short*)alloc((size_t)E_ * E_ * 2);
    short* qbuf  = (short*)alloc((size_t)MROWS * E_ * 2);
    short* kbuf  = (short*)alloc((size_t)MROWS * E_ * 2);
    short* vtb   = (short*)alloc((size_t)32 * 64 * 2048 * 2);
    float* xpart = (float*)alloc((size_t)64 * B_ * E_ * 4);
    float* tb    = (float*)alloc((size_t)B_ * H_ * E_ * 4);
    float* scorp = (float*)alloc((size_t)4 * B_ * H_ * L_ * 4);
    short* selkb = (short*)alloc((size_t)32 * 4096 * 2);
    float* wpart = (float*)alloc((size_t)16 * 32 * 4096 * 4);
    short* att   = (short*)alloc((size_t)MROWS * E_ * 2);

    // stage 1: xsum-first merged prep; qsum+t
    k_prep<<<8704, 256, 0, stream>>>(query, q_w, k_w, v_w, o_w, xb, qwb, kwb, vwb, owb, xpart);
    k_qt<<<32, 256, 0, stream>>>(xpart, q_w, q_b, k_w, tb);

    // stage 2: fused q/k/v projections + score blocks in ONE dispatch (overlap)
    k_gemm3<<<1024, 512, 65536, stream>>>(xb, qwb, kwb, vwb, q_b, k_b, v_b,
                                          qbuf, kbuf, vtb, query, tb, scorp);

    // stage 3: top-k select (ballot counting) + gather
    k_sel<<<8, 256, 0, stream>>>(scorp, kbuf, selkb);

    // stage 4: MFMA attention core (wreduce folded into attO's LDS prologue)
    k_attW<<<512, 256, 0, stream>>>(kbuf, vtb, selkb, wpart);
    k_attO<<<512, 256, 0, stream>>>(qbuf, selkb, wpart, att);

    // stage 5: o-projection fused with bias + residual + transpose back
    k_gemmo<<<512, 512, 49152, stream>>>(att, owb, o_b, out, query);
}

// Round 17
// 123.420 us; speedup vs baseline: 1.0787x; 1.0787x over previous
//
#include <hip/hip_runtime.h>
#include <hip/hip_bf16.h>

#define L_ 2048
#define B_ 2
#define E_ 1024
#define H_ 16
#define HD_ 64
#define TOPK_ 64
#define MROWS (B_*L_)
#define SCALE 0.125f

typedef __attribute__((ext_vector_type(8))) short short8;
typedef __attribute__((ext_vector_type(4))) short short4v;
typedef __attribute__((ext_vector_type(4))) float f32x4;

static __device__ __forceinline__ short f2bf(float f) {
    __hip_bfloat16 h = __float2bfloat16(f);
    return *reinterpret_cast<short*>(&h);
}

// ---- merged: xsum partials FIRST (512 blks, 4-acc unrolled) + transpose + casts ----
__global__ void k_prep(const float* __restrict__ q,
                       const float* __restrict__ w0, const float* __restrict__ w1,
                       const float* __restrict__ w2, const float* __restrict__ w3,
                       short* __restrict__ xb,
                       short* __restrict__ o0, short* __restrict__ o1,
                       short* __restrict__ o2, short* __restrict__ o3,
                       float* __restrict__ xpart) {
    int blk = blockIdx.x;
    if (blk < 512) {
        int cg = blk & 7, ch = blk >> 3;   // ch 0..63
        int col = cg * 256 + threadIdx.x;
        const float* qp = q + (size_t)(ch * 32) * (B_ * E_) + col;
        float s0 = 0.f, s1 = 0.f, s2 = 0.f, s3 = 0.f;
#pragma unroll
        for (int l = 0; l < 32; l += 4) {
            s0 += qp[(size_t)(l + 0) * (B_ * E_)];
            s1 += qp[(size_t)(l + 1) * (B_ * E_)];
            s2 += qp[(size_t)(l + 2) * (B_ * E_)];
            s3 += qp[(size_t)(l + 3) * (B_ * E_)];
        }
        xpart[ch * (B_ * E_) + col] = (s0 + s1) + (s2 + s3);
    } else if (blk < 4608) {
        int i = (blk - 512) * 256 + threadIdx.x;
        int idx = i * 4;
        int e = idx & (E_ - 1);
        int l = (idx >> 10) & (L_ - 1);
        int b = idx >> 21;
        float4 v = *reinterpret_cast<const float4*>(q + l * (B_ * E_) + b * E_ + e);
        short4v o;
        o[0] = f2bf(v.x); o[1] = f2bf(v.y); o[2] = f2bf(v.z); o[3] = f2bf(v.w);
        *reinterpret_cast<short4v*>(xb + idx) = o;
    } else {
        int cb = blk - 4608;
        int sel = cb >> 10, lb = cb & 1023;
        const float* w = sel == 0 ? w0 : sel == 1 ? w1 : sel == 2 ? w2 : w3;
        short* o = sel == 0 ? o0 : sel == 1 ? o1 : sel == 2 ? o2 : o3;
        int i = lb * 256 + threadIdx.x;
        float4 v = *reinterpret_cast<const float4*>(w + i * 4);
        short4v s;
        s[0] = f2bf(v.x); s[1] = f2bf(v.y); s[2] = f2bf(v.z); s[3] = f2bf(v.w);
        *reinterpret_cast<short4v*>(o + i * 4) = s;
    }
}

// ---- GEMM core: dbuf 2-phase + T2 swizzle, 512 threads / 8 waves.
// Compile-time MODE + dynamic LDS (rounds 11-13 lessons).
template<int MODE, int BM, int BN>
__device__ __forceinline__ void gemm_body(const short* __restrict__ A,
                                          const short* __restrict__ Bw,
                                          const float* __restrict__ bias,
                                          short* __restrict__ Cb,
                                          float* __restrict__ Cf,
                                          const float* __restrict__ ident,
                                          int bx, int by) {
    const int K = E_;
    constexpr int MI = BM / 32;
    constexpr int NI = BN / 64;
    extern __shared__ short smem[];
    short* As = smem;
    short* Bs = smem + 2 * BM * 64;
    int tid = threadIdx.x;
    int lane = tid & 63;
    int wid = tid >> 6;
    int wr = wid >> 2, wc = wid & 3;
    int lrow = lane & 15;
    int kg = lane >> 4;
    int lr8 = lane >> 3;
    int swz = (((lane & 7) ^ (lr8 & 7)) * 8);
    int rx = lrow & 7;
    int mBase = by * BM, nBase = bx * BN;

    auto STAGE = [&](int buf, int k0) {
#pragma unroll
        for (int i = 0; i < BM / 64; ++i) {
            int r0 = (wid * (BM / 64) + i) * 8;
            const short* ga = A + (size_t)(mBase + r0 + lr8) * K + k0 + swz;
            __builtin_amdgcn_global_load_lds(
                (const __attribute__((address_space(1))) void*)ga,
                (__attribute__((address_space(3))) void*)(As + buf * BM * 64 + r0 * 64), 16, 0, 0);
        }
#pragma unroll
        for (int i = 0; i < BN / 64; ++i) {
            int r0 = (wid * (BN / 64) + i) * 8;
            const short* gb = Bw + (size_t)(nBase + r0 + lr8) * K + k0 + swz;
            __builtin_amdgcn_global_load_lds(
                (const __attribute__((address_space(1))) void*)gb,
                (__attribute__((address_space(3))) void*)(Bs + buf * BN * 64 + r0 * 64), 16, 0, 0);
        }
    };

    f32x4 acc[MI][NI];
#pragma unroll
    for (int i = 0; i < MI; ++i)
#pragma unroll
        for (int j = 0; j < NI; ++j) acc[i][j] = (f32x4){0.f, 0.f, 0.f, 0.f};

    STAGE(0, 0);
    asm volatile("s_waitcnt vmcnt(0)" ::: "memory");
    __syncthreads();

    int cur = 0;
    for (int k0 = 0; k0 < K; k0 += 64) {
        if (k0 + 64 < K) STAGE(cur ^ 1, k0 + 64);

        short8 af[2][MI], bf[2][NI];
#pragma unroll
        for (int kk = 0; kk < 2; ++kk) {
#pragma unroll
            for (int mi = 0; mi < MI; ++mi)
                af[kk][mi] = *reinterpret_cast<const short8*>(
                    As + cur * BM * 64 + (wr * (MI * 16) + mi * 16 + lrow) * 64 + (((kk * 4 + kg) ^ rx) * 8));
#pragma unroll
            for (int ni = 0; ni < NI; ++ni)
                bf[kk][ni] = *reinterpret_cast<const short8*>(
                    Bs + cur * BN * 64 + (wc * (NI * 16) + ni * 16 + lrow) * 64 + (((kk * 4 + kg) ^ rx) * 8));
        }
#pragma unroll
        for (int kk = 0; kk < 2; ++kk)
#pragma unroll
            for (int mi = 0; mi < MI; ++mi)
#pragma unroll
                for (int ni = 0; ni < NI; ++ni)
                    acc[mi][ni] = __builtin_amdgcn_mfma_f32_16x16x32_bf16(
                        af[kk][mi], bf[kk][ni], acc[mi][ni], 0, 0, 0);

        asm volatile("s_waitcnt vmcnt(0)" ::: "memory");
        __syncthreads();
        cur ^= 1;
    }

    int rowq = (lane >> 4) * 4;
    int coll = lane & 15;
#pragma unroll
    for (int mi = 0; mi < MI; ++mi) {
#pragma unroll
        for (int ni = 0; ni < NI; ++ni) {
            int col = nBase + wc * (NI * 16) + ni * 16 + coll;
            float bv = bias[col];
            int row0 = mBase + wr * (MI * 16) + mi * 16 + rowq;
            if (MODE == 2) {
                int b = row0 >> 11, l = row0 & (L_ - 1);
                short4v sv;
#pragma unroll
                for (int r = 0; r < 4; ++r) sv[r] = f2bf(acc[mi][ni][r] + bv);
                *reinterpret_cast<short4v*>(
                    Cb + ((size_t)((b * H_ + (col >> 6)) * 64 + (col & 63))) * 2048 + l) = sv;
            } else if (MODE == 1) {
#pragma unroll
                for (int r = 0; r < 4; ++r) {
                    int row = row0 + r;
                    int b = row >> 11, l = row & (L_ - 1);
                    size_t oi = (size_t)l * (B_ * E_) + b * E_ + col;
                    Cf[oi] = acc[mi][ni][r] + bv + ident[oi];
                }
            } else {
#pragma unroll
                for (int r = 0; r < 4; ++r)
                    Cb[(size_t)(row0 + r) * E_ + col] = f2bf(acc[mi][ni][r] + bv);
            }
        }
    }
}

// ---- score body (512 threads): partial scores over e-quarters; same per-(h,n)
// f32 summation order -> bit-identical scorp -> identical top-k ----
__device__ __forceinline__ void score_body(const float* __restrict__ query,
                                           const float* __restrict__ tb,
                                           float* __restrict__ scorp, int id) {
    extern __shared__ short smem[];
    float* xs = (float*)smem;             // [64][68]
    float* ts = (float*)smem + 64 * 68;   // [16][68]
    int eq = id >> 6;
    int b = (id >> 5) & 1;
    int n0 = (id & 31) * 64;
    int tid = threadIdx.x;                // 0..511
    int hg = tid & 7, rg = tid >> 3;      // rg 0..63
    float acc0 = 0.f, acc1 = 0.f;
    for (int e0 = eq * 256; e0 < eq * 256 + 256; e0 += 64) {
        __syncthreads();
        for (int j = tid; j < 1024; j += 512) {
            int r = j >> 4, c4 = (j & 15) * 4;
            float4 v = *reinterpret_cast<const float4*>(
                &query[(size_t)(n0 + r) * (B_ * E_) + b * E_ + e0 + c4]);
            *reinterpret_cast<float4*>(&xs[r * 68 + c4]) = v;
        }
        if (tid < 256) {
            int hh = tid >> 4, c4 = (tid & 15) * 4;
            float4 v = *reinterpret_cast<const float4*>(&tb[(size_t)(b * 16 + hh) * E_ + e0 + c4]);
            *reinterpret_cast<float4*>(&ts[hh * 68 + c4]) = v;
        }
        __syncthreads();
        for (int c = 0; c < 64; ++c) {
            float x0 = xs[rg * 68 + c];
            acc0 += x0 * ts[hg * 68 + c];
            acc1 += x0 * ts[(hg + 8) * 68 + c];
        }
    }
    scorp[(size_t)eq * 65536 + (size_t)(b * 16 + hg) * L_ + n0 + rg] = acc0;
    scorp[(size_t)eq * 65536 + (size_t)(b * 16 + hg + 8) * L_ + n0 + rg] = acc1;
}

// ---- merged dispatch: blocks 0..767 = q/k/v projections; 768..1023 = scores ----
__global__ __launch_bounds__(512) void k_gemm3(const short* __restrict__ A,
    const short* __restrict__ W0, const short* __restrict__ W1, const short* __restrict__ W2,
    const float* __restrict__ b0, const float* __restrict__ b1, const float* __restrict__ b2,
    short* __restrict__ C0, short* __restrict__ C1, short* __restrict__ vtb,
    const float* __restrict__ query, const float* __restrict__ tb,
    float* __restrict__ scorp) {
    int wg = blockIdx.x;
    if (wg < 768) {
        int sw = (wg & 7) * 96 + (wg >> 3);
        int bx = sw & 7, by = (sw >> 3) & 31, z = sw >> 8;
        if (z == 2)
            gemm_body<2, 128, 128>(A, W2, b2, vtb, nullptr, nullptr, bx, by);
        else if (z == 1)
            gemm_body<0, 128, 128>(A, W1, b1, C1, nullptr, nullptr, bx, by);
        else
            gemm_body<0, 128, 128>(A, W0, b0, C0, nullptr, nullptr, bx, by);
    } else {
        score_body(query, tb, scorp, wg - 768);
    }
}

__global__ __launch_bounds__(512) void k_gemmo(const short* __restrict__ A,
                                               const short* __restrict__ Bw,
                                               const float* __restrict__ bias,
                                               float* __restrict__ C,
                                               const float* __restrict__ ident) {
    int wg = blockIdx.x;
    int sw = (wg & 7) * 64 + (wg >> 3);
    int bx = sw & 15, by = sw >> 4;
    gemm_body<1, 128, 64>(A, Bw, bias, nullptr, C, ident, bx, by);
}

// ---- fused qsum + t: per (b,h) block computes t[b,h,:] from xpart (f32 exact) ----
__global__ __launch_bounds__(256) void k_qt(const float* __restrict__ xpart,
                                            const float* __restrict__ qw,
                                            const float* __restrict__ qb,
                                            const float* __restrict__ kw,
                                            float* __restrict__ tb) {
    __shared__ float xs[1024];
    __shared__ float pr[256];
    __shared__ float qs[64];
    int bh = blockIdx.x;              // grid 32
    int b = bh >> 4, h = bh & 15;
    int tid = threadIdx.x;
    for (int j = tid; j < 1024; j += 256) {
        float s = 0.f;
#pragma unroll
        for (int c = 0; c < 64; ++c) s += xpart[c * (B_ * E_) + b * E_ + j];
        xs[j] = s;
    }
    __syncthreads();
    int fl = tid >> 2, eq = tid & 3;
    int f = h * 64 + fl;
    float s = 0.f;
    for (int e = eq * 256; e < eq * 256 + 256; ++e) s += xs[e] * qw[(size_t)f * E_ + e];
    pr[tid] = s;
    __syncthreads();
    if (eq == 0)
        qs[fl] = ((pr[tid] + pr[tid + 1]) + pr[tid + 2]) + pr[tid + 3] + (float)L_ * qb[f];
    __syncthreads();
    float acc[4] = {0.f, 0.f, 0.f, 0.f};
    for (int d = 0; d < 64; ++d) {
        float qv = qs[d];
        float4 kv = *reinterpret_cast<const float4*>(kw + (size_t)(h * 64 + d) * E_ + tid * 4);
        acc[0] += qv * kv.x; acc[1] += qv * kv.y; acc[2] += qv * kv.z; acc[3] += qv * kv.w;
    }
    float4 o; o.x = acc[0]; o.y = acc[1]; o.z = acc[2]; o.w = acc[3];
    *reinterpret_cast<float4*>(tb + (size_t)bh * E_ + tid * 4) = o;
}

// ---- top-64 per (b,h): ballot-based radix-select + wide gather ----
__global__ __launch_bounds__(256) void k_sel(const float* __restrict__ scorp,
                                             const short* __restrict__ kb,
                                             short* __restrict__ selkb) {
    __shared__ int sel[4][64];
    int tid = threadIdx.x;
    int wid = tid >> 6, lane = tid & 63;
    int bh = blockIdx.x * 4 + wid;   // grid 8
    int b = bh >> 4, h = bh & 15;

    unsigned u[32];
#pragma unroll
    for (int j = 0; j < 32; ++j) {
        int base = bh * L_ + j * 64 + lane;
        float sc = ((scorp[base] + scorp[base + 65536]) + scorp[base + 131072]) + scorp[base + 196608];
        sc *= SCALE;
        unsigned bits = __float_as_uint(sc);
        u[j] = (bits & 0x80000000u) ? ~bits : (bits | 0x80000000u);
    }
    unsigned prefix = 0;
    int k = TOPK_;
    for (int bit = 31; bit >= 0; --bit) {
        unsigned cand = prefix | (1u << bit);
        unsigned cs = cand >> bit;
        int c = 0;
#pragma unroll
        for (int j = 0; j < 32; ++j)
            c += __popcll(__ballot((u[j] >> bit) == cs));
        if (c >= k) prefix = cand; else k -= c;
    }
    unsigned T = prefix;
    int nStrict = 0;
#pragma unroll
    for (int j = 0; j < 32; ++j) nStrict += __popcll(__ballot(u[j] > T));
    int nTies = TOPK_ - nStrict;

    int strictBase = 0, tieBase = 0;
    unsigned long long below = (lane == 0) ? 0ull : ((~0ull) >> (64 - lane));
#pragma unroll
    for (int j = 0; j < 32; ++j) {
        unsigned long long mS = __ballot(u[j] > T);
        unsigned long long mT = __ballot(u[j] == T);
        if (u[j] > T) {
            int slot = strictBase + __popcll(mS & below);
            sel[wid][slot] = j * 64 + lane;
        } else if (u[j] == T) {
            int r = tieBase + __popcll(mT & below);
            if (r < nTies) sel[wid][nStrict + r] = j * 64 + lane;
        }
        strictBase += __popcll(mS);
        tieBase += __popcll(mT);
    }
    __syncthreads();

    int idx8[8];
#pragma unroll
    for (int it = 0; it < 8; ++it) idx8[it] = sel[wid][it * 8 + (lane >> 3)];
#pragma unroll
    for (int it = 0; it < 8; ++it) {
        int m = it * 8 + (lane >> 3);
        const short* src = kb + ((size_t)b * L_ + idx8[it]) * E_ + h * HD_ + (lane & 7) * 8;
        short8 v = *reinterpret_cast<const short8*>(src);
        *reinterpret_cast<short8*>(
            selkb + (size_t)bh * 4096 + m * 64 + (((lane & 7) ^ (m & 7)) * 8)) = v;
    }
}

// ---- attW: S_k = k.selk^T (MFMA) -> softmax -> Wpart = P2^T v (MFMA) ----
__global__ __launch_bounds__(256) void k_attW(const short* __restrict__ kb,
                                              const short* __restrict__ vtb,
                                              const short* __restrict__ selkb,
                                              float* __restrict__ wpart) {
    __shared__ short sk[4096], kt[4096], vt[4096], pt[4096];
    int wg = blockIdx.x;
    int sw = (wg & 7) * 64 + (wg >> 3);
    int bh = sw & 31, ch = sw >> 5;
    int b = bh >> 4, h = bh & 15;
    int tid = threadIdx.x, w = tid >> 6, lane = tid & 63;
    int lr = lane & 15, kg = lane >> 4;

#pragma unroll
    for (int j = 0; j < 2; ++j) {
        int off = (w * 2 + j) * 512;
        __builtin_amdgcn_global_load_lds(
            (const __attribute__((address_space(1))) void*)(selkb + (size_t)bh * 4096 + off + lane * 8),
            (__attribute__((address_space(3))) void*)(sk + off), 16, 0, 0);
    }

    f32x4 accw[4];
#pragma unroll
    for (int i = 0; i < 4; ++i) accw[i] = (f32x4){0.f, 0.f, 0.f, 0.f};

    for (int t = 0; t < 2; ++t) {
        int lt = ch * 128 + t * 64;
#pragma unroll
        for (int j = 0; j < 2; ++j) {
            int r = w * 16 + j * 8 + (lane >> 3);
            int s = lane & 7;
            const short* src = kb + ((size_t)(b * L_ + lt + r)) * E_ + h * 64 + ((s ^ (r & 7)) * 8);
            __builtin_amdgcn_global_load_lds(
                (const __attribute__((address_space(1))) void*)src,
                (__attribute__((address_space(3))) void*)(kt + (w * 16 + j * 8) * 64), 16, 0, 0);
        }
        __syncthreads();

        f32x4 s4[4];
#pragma unroll
        for (int i = 0; i < 4; ++i) s4[i] = (f32x4){0.f, 0.f, 0.f, 0.f};
#pragma unroll
        for (int kk = 0; kk < 2; ++kk) {
            int row = w * 16 + lr;
            short8 a = *reinterpret_cast<const short8*>(
                kt + row * 64 + (((kk * 4 + kg) ^ (row & 7)) * 8));
#pragma unroll
            for (int ni = 0; ni < 4; ++ni) {
                int m = ni * 16 + lr;
                short8 bb = *reinterpret_cast<const short8*>(
                    sk + m * 64 + (((kk * 4 + kg) ^ (m & 7)) * 8));
                s4[ni] = __builtin_amdgcn_mfma_f32_16x16x32_bf16(a, bb, s4[ni], 0, 0, 0);
            }
        }
        float p[4][4];
#pragma unroll
        for (int r = 0; r < 4; ++r) {
            float v0 = s4[0][r] * SCALE, v1 = s4[1][r] * SCALE;
            float v2 = s4[2][r] * SCALE, v3 = s4[3][r] * SCALE;
            float mx = fmaxf(fmaxf(v0, v1), fmaxf(v2, v3));
            mx = fmaxf(mx, __shfl_xor(mx, 1));
            mx = fmaxf(mx, __shfl_xor(mx, 2));
            mx = fmaxf(mx, __shfl_xor(mx, 4));
            mx = fmaxf(mx, __shfl_xor(mx, 8));
            float e0 = __expf(v0 - mx), e1 = __expf(v1 - mx);
            float e2 = __expf(v2 - mx), e3 = __expf(v3 - mx);
            float sm = e0 + e1 + e2 + e3;
            sm += __shfl_xor(sm, 1);
            sm += __shfl_xor(sm, 2);
            sm += __shfl_xor(sm, 4);
            sm += __shfl_xor(sm, 8);
            float inv = 1.f / sm;
            p[0][r] = e0 * inv; p[1][r] = e1 * inv; p[2][r] = e2 * inv; p[3][r] = e3 * inv;
        }
#pragma unroll
        for (int ni = 0; ni < 4; ++ni)
#pragma unroll
            for (int r = 0; r < 4; ++r) {
                int m = ni * 16 + lr;
                int ll = w * 16 + kg * 4 + r;
                pt[m * 64 + (((ll >> 3) ^ (m & 7)) * 8) + (ll & 7)] = f2bf(p[ni][r]);
            }
#pragma unroll
        for (int j = 0; j < 2; ++j) {
            int d = w * 16 + j * 8 + (lane >> 3);
            int s = lane & 7;
            const short* src = vtb + ((size_t)(bh * 64 + d)) * 2048 + lt + ((s ^ (d & 7)) * 8);
            __builtin_amdgcn_global_load_lds(
                (const __attribute__((address_space(1))) void*)src,
                (__attribute__((address_space(3))) void*)(vt + (w * 16 + j * 8) * 64), 16, 0, 0);
        }
        __syncthreads();
#pragma unroll
        for (int kk = 0; kk < 2; ++kk) {
            int mm = w * 16 + lr;
            short8 a = *reinterpret_cast<const short8*>(
                pt + mm * 64 + (((kk * 4 + kg) ^ (mm & 7)) * 8));
#pragma unroll
            for (int ni = 0; ni < 4; ++ni) {
                int d = ni * 16 + lr;
                short8 bb = *reinterpret_cast<const short8*>(
                    vt + d * 64 + (((kk * 4 + kg) ^ (d & 7)) * 8));
                accw[ni] = __builtin_amdgcn_mfma_f32_16x16x32_bf16(a, bb, accw[ni], 0, 0, 0);
            }
        }
    }
#pragma unroll
    for (int ni = 0; ni < 4; ++ni)
#pragma unroll
        for (int r = 0; r < 4; ++r) {
            int m = w * 16 + kg * 4 + r;
            int d = ni * 16 + lr;
            wpart[((size_t)(ch * 32 + bh)) * 4096 + m * 64 + d] = accw[ni][r];
        }
}

// ---- reduce wpart chunks -> Wt global bf16, transposed + pre-swizzled ----
__global__ void k_wreduce(const float* __restrict__ wpart, short* __restrict__ wtg) {
    int i = blockIdx.x * 256 + threadIdx.x;  // 131072, grid 512
    float s = 0.f;
#pragma unroll
    for (int c = 0; c < 16; ++c) s += wpart[(size_t)c * 131072 + i];
    int bh = i >> 12, m = (i >> 6) & 63, d = i & 63;
    wtg[(size_t)bh * 4096 + d * 64 + (((m >> 3) ^ (d & 7)) * 8) + (m & 7)] = f2bf(s);
}

// ---- attO: S_q = q.selk^T (MFMA) -> softmax -> att = P1.W (MFMA) -> bf16 ----
__global__ __launch_bounds__(256) void k_attO(const short* __restrict__ qb,
                                              const short* __restrict__ selkb,
                                              const short* __restrict__ wtg,
                                              short* __restrict__ att) {
    __shared__ short sk[4096], wt[4096], qt[4096], p1[4096];
    int wg = blockIdx.x;
    int sw = (wg & 7) * 64 + (wg >> 3);
    int bh = sw & 31, ch = sw >> 5;
    int b = bh >> 4, h = bh & 15;
    int tid = threadIdx.x, w = tid >> 6, lane = tid & 63;
    int lr = lane & 15, kg = lane >> 4;

#pragma unroll
    for (int j = 0; j < 2; ++j) {
        int off = (w * 2 + j) * 512;
        __builtin_amdgcn_global_load_lds(
            (const __attribute__((address_space(1))) void*)(selkb + (size_t)bh * 4096 + off + lane * 8),
            (__attribute__((address_space(3))) void*)(sk + off), 16, 0, 0);
        __builtin_amdgcn_global_load_lds(
            (const __attribute__((address_space(1))) void*)(wtg + (size_t)bh * 4096 + off + lane * 8),
            (__attribute__((address_space(3))) void*)(wt + off), 16, 0, 0);
    }

    for (int t = 0; t < 2; ++t) {
        int lt = ch * 128 + t * 64;
#pragma unroll
        for (int j = 0; j < 2; ++j) {
            int r = w * 16 + j * 8 + (lane >> 3);
            int s = lane & 7;
            const short* src = qb + ((size_t)(b * L_ + lt + r)) * E_ + h * 64 + ((s ^ (r & 7)) * 8);
            __builtin_amdgcn_global_load_lds(
                (const __attribute__((address_space(1))) void*)src,
                (__attribute__((address_space(3))) void*)(qt + (w * 16 + j * 8) * 64), 16, 0, 0);
        }
        __syncthreads();

        f32x4 s4[4];
#pragma unroll
        for (int i = 0; i < 4; ++i) s4[i] = (f32x4){0.f, 0.f, 0.f, 0.f};
#pragma unroll
        for (int kk = 0; kk < 2; ++kk) {
            int row = w * 16 + lr;
            short8 a = *reinterpret_cast<const short8*>(
                qt + row * 64 + (((kk * 4 + kg) ^ (row & 7)) * 8));
#pragma unroll
            for (int ni = 0; ni < 4; ++ni) {
                int m = ni * 16 + lr;
                short8 bb = *reinterpret_cast<const short8*>(
                    sk + m * 64 + (((kk * 4 + kg) ^ (m & 7)) * 8));
                s4[ni] = __builtin_amdgcn_mfma_f32_16x16x32_bf16(a, bb, s4[ni], 0, 0, 0);
            }
        }
        float p[4][4];
#pragma unroll
        for (int r = 0; r < 4; ++r) {
            float v0 = s4[0][r] * SCALE, v1 = s4[1][r] * SCALE;
            float v2 = s4[2][r] * SCALE, v3 = s4[3][r] * SCALE;
            float mx = fmaxf(fmaxf(v0, v1), fmaxf(v2, v3));
            mx = fmaxf(mx, __shfl_xor(mx, 1));
            mx = fmaxf(mx, __shfl_xor(mx, 2));
            mx = fmaxf(mx, __shfl_xor(mx, 4));
            mx = fmaxf(mx, __shfl_xor(mx, 8));
            float e0 = __expf(v0 - mx), e1 = __expf(v1 - mx);
            float e2 = __expf(v2 - mx), e3 = __expf(v3 - mx);
            float sm = e0 + e1 + e2 + e3;
            sm += __shfl_xor(sm, 1);
            sm += __shfl_xor(sm, 2);
            sm += __shfl_xor(sm, 4);
            sm += __shfl_xor(sm, 8);
            float inv = 1.f / sm;
            p[0][r] = e0 * inv; p[1][r] = e1 * inv; p[2][r] = e2 * inv; p[3][r] = e3 * inv;
        }
#pragma unroll
        for (int ni = 0; ni < 4; ++ni)
#pragma unroll
            for (int r = 0; r < 4; ++r) {
                int m = ni * 16 + lr;
                int ll = w * 16 + kg * 4 + r;
                p1[ll * 64 + (((m >> 3) ^ (ll & 7)) * 8) + (m & 7)] = f2bf(p[ni][r]);
            }
        __syncthreads();
        f32x4 ao[4];
#pragma unroll
        for (int i = 0; i < 4; ++i) ao[i] = (f32x4){0.f, 0.f, 0.f, 0.f};
#pragma unroll
        for (int kk = 0; kk < 2; ++kk) {
            int row = w * 16 + lr;
            short8 a = *reinterpret_cast<const short8*>(
                p1 + row * 64 + (((kk * 4 + kg) ^ (row & 7)) * 8));
#pragma unroll
            for (int ni = 0; ni < 4; ++ni) {
                int d = ni * 16 + lr;
                short8 bb = *reinterpret_cast<const short8*>(
                    wt + d * 64 + (((kk * 4 + kg) ^ (d & 7)) * 8));
                ao[ni] = __builtin_amdgcn_mfma_f32_16x16x32_bf16(a, bb, ao[ni], 0, 0, 0);
            }
        }
#pragma unroll
        for (int ni = 0; ni < 4; ++ni)
#pragma unroll
            for (int r = 0; r < 4; ++r) {
                int l = lt + w * 16 + kg * 4 + r;
                int d = ni * 16 + lr;
                att[((size_t)(b * L_ + l)) * E_ + h * 64 + d] = f2bf(ao[ni][r]);
            }
    }
}

extern "C" void kernel_launch(void* const* d_in, const int* in_sizes, int n_in,
                              void* d_out, int out_size, void* d_ws, size_t ws_size,
                              hipStream_t stream) {
    const float* query = (const float*)d_in[0];
    const float* q_w = (const float*)d_in[1];
    const float* q_b = (const float*)d_in[2];
    const float* k_w = (const float*)d_in[3];
    const float* k_b = (const float*)d_in[4];
    const float* v_w = (const float*)d_in[5];
    const float* v_b = (const float*)d_in[6];
    const float* o_w = (const float*)d_in[7];
    const float* o_b = (const float*)d_in[8];
    float* out = (float*)d_out;

    char* p = (char*)d_ws;
    auto alloc = [&](size_t bytes) {
        char* r = p;
        p += (bytes + 255) & ~(size_t)255;
        return r;
    };
    short* xb    = (short*)alloc((size_t)MROWS * E_ * 2);
    short* qwb   = (short*)alloc((size_t)E_ * E_ * 2);
    short* kwb   = (short*)alloc((size_t)E_ * E_ * 2);
    short* vwb   = (short*)alloc((size_t)E_ * E_ * 2);
    short* owb   = (short*)alloc((size_t)E_ * E_ * 2);
    short* qbuf  = (short*)alloc((size_t)MROWS * E_ * 2);
    short* kbuf  = (short*)alloc((size_t)MROWS * E_ * 2);
    short* vtb   = (short*)alloc((size_t)32 * 64 * 2048 * 2);
    float* xpart = (float*)alloc((size_t)64 * B_ * E_ * 4);
    float* tb    = (float*)alloc((size_t)B_ * H_ * E_ * 4);
    float* scorp = (float*)alloc((size_t)4 * B_ * H_ * L_ * 4);
    short* selkb = (short*)alloc((size_t)32 * 4096 * 2);
    short* wtg   = (short*)alloc((size_t)32 * 4096 * 2);
    float* wpart = (float*)alloc((size_t)16 * 32 * 4096 * 4);
    short* att   = (short*)alloc((size_t)MROWS * E_ * 2);

    // stage 1: xsum-first merged prep; qsum+t
    k_prep<<<8704, 256, 0, stream>>>(query, q_w, k_w, v_w, o_w, xb, qwb, kwb, vwb, owb, xpart);
    k_qt<<<32, 256, 0, stream>>>(xpart, q_w, q_b, k_w, tb);

    // stage 2: fused q/k/v projections + score blocks in ONE dispatch (overlap)
    k_gemm3<<<1024, 512, 65536, stream>>>(xb, qwb, kwb, vwb, q_b, k_b, v_b,
                                          qbuf, kbuf, vtb, query, tb, scorp);

    // stage 3: top-k select (ballot counting) + gather
    k_sel<<<8, 256, 0, stream>>>(scorp, kbuf, selkb);

    // stage 4: MFMA attention core
    k_attW<<<512, 256, 0, stream>>>(kbuf, vtb, selkb, wpart);
    k_wreduce<<<512, 256, 0, stream>>>(wpart, wtg);
    k_attO<<<512, 256, 0, stream>>>(qbuf, selkb, wtg, att);

    // stage 5: o-projection fused with bias + residual + transpose back
    k_gemmo<<<512, 512, 49152, stream>>>(att, owb, o_b, out, query);
}